// Round 2
// baseline (6720.111 us; speedup 1.0000x reference)
//
#include <hip/hip_runtime.h>
#include <math.h>

#define BB 32
#define LL 1024
#define DD 256
#define HH 256
#define NG 7
#define HW (HH*HH)       /* 65536 */
#define WhS (2*HH*HH)    /* Wh per-gate stride */

__device__ __forceinline__ float sigm(float x){ return 1.0f/(1.0f + expf(-x)); }
__device__ __forceinline__ float4 ld4(const float* p){ return *reinterpret_cast<const float4*>(p); }
__device__ __forceinline__ void st4(float* p, float4 v){ *reinterpret_cast<float4*>(p) = v; }
__device__ __forceinline__ float4 f4z(){ return make_float4(0.f,0.f,0.f,0.f); }
__device__ __forceinline__ float4 f4add(float4 a, float4 b){ return make_float4(a.x+b.x,a.y+b.y,a.z+b.z,a.w+b.w); }
__device__ __forceinline__ float4 f4scale(float4 a, float s){ return make_float4(a.x*s,a.y*s,a.z*s,a.w*s); }

// h = (init_h*0.1-0.05)*fm ; c likewise
__global__ __launch_bounds__(256) void k_init(const float* __restrict__ ih, const float* __restrict__ ic,
    const int* __restrict__ mask, float* __restrict__ h, float* __restrict__ c){
  size_t n = (size_t)BB*LL*HH;
  for (size_t idx = (size_t)blockIdx.x*256 + threadIdx.x; idx < n; idx += (size_t)gridDim.x*256){
    size_t bl = idx >> 8;
    float fm = (float)mask[bl];
    h[idx] = (ih[idx]*0.1f - 0.05f)*fm;
    c[idx] = (ic[idx]*0.1f - 0.05f)*fm;
  }
}

// comb = mean_l h ; combc = mean_l c
__global__ __launch_bounds__(256) void k_mean(const float* __restrict__ h, const float* __restrict__ c,
    float* __restrict__ comb, float* __restrict__ combc){
  int b = blockIdx.x, k = threadIdx.x;
  const float* hp = h + (size_t)b*LL*HH + k;
  const float* cp = c + (size_t)b*LL*HH + k;
  float sh = 0.f, sc = 0.f;
  for (int l = 0; l < LL; ++l){ sh += hp[(size_t)l*HH]; sc += cp[(size_t)l*HH]; }
  comb[b*HH+k]  = sh*(1.0f/LL);
  combc[b*HH+k] = sc*(1.0f/LL);
}

// small (B,H) GEMMs: g_d, g_o, gx2f = dh@gWx2+gb2, wd[g] = dh@Wd[g]+b[g]
__global__ __launch_bounds__(256) void k_small(const float* __restrict__ dh, const float* __restrict__ comb,
    const float* __restrict__ gWx, const float* __restrict__ gWh, const float* __restrict__ gb,
    const float* __restrict__ Wd, const float* __restrict__ bias,
    float* __restrict__ g_d, float* __restrict__ g_o, float* __restrict__ gx2f, float* __restrict__ wd){
  __shared__ float dsh[HH], csh[HH];
  int b = blockIdx.x, k = threadIdx.x;
  dsh[k] = dh[b*HH+k]; csh[k] = comb[b*HH+k];
  __syncthreads();
  float ad = gb[0*HH+k], ao = gb[1*HH+k], ax = gb[2*HH+k];
  for (int j = 0; j < HH; ++j){
    float dv = dsh[j], cv = csh[j];
    ad += dv*gWx[j*HH+k]      + cv*gWh[j*HH+k];
    ao += dv*gWx[HW + j*HH+k] + cv*gWh[HW + j*HH+k];
    ax += dv*gWx[2*HW + j*HH+k];
  }
  g_d[b*HH+k] = sigm(ad);
  g_o[b*HH+k] = sigm(ao);
  gx2f[b*HH+k] = ax;
  for (int g = 0; g < NG; ++g){
    float aw = bias[g*HH+k];
    const float* W = Wd + (size_t)g*HW + k;
    for (int j = 0; j < HH; ++j) aw += dsh[j]*W[(size_t)j*HH];
    wd[(size_t)(g*BB + b)*HH + k] = aw;
  }
}

// Y = h @ gWh[2]  (M=32768, N=256, K=256)
__global__ __launch_bounds__(256) void k_gemm_gf(const float* __restrict__ h, const float* __restrict__ W,
    float* __restrict__ Y){
  __shared__ float As[64][17];
  __shared__ __align__(16) float Ws[16][64];
  int m0 = blockIdx.x*64, k0 = blockIdx.y*64;
  int tid = threadIdx.x, tx = tid & 15, ty = tid >> 4;
  float acc[4][4];
  #pragma unroll
  for (int i=0;i<4;++i){ acc[i][0]=0.f; acc[i][1]=0.f; acc[i][2]=0.f; acc[i][3]=0.f; }
  for (int kc = 0; kc < 16; ++kc){
    int cb = kc*16;
    { int r = tid >> 2, c0 = (tid & 3)*4;
      float4 v = ld4(h + (size_t)(m0+r)*HH + cb + c0);
      As[r][c0+0]=v.x; As[r][c0+1]=v.y; As[r][c0+2]=v.z; As[r][c0+3]=v.w; }
    { int kk = tid >> 4, c0 = (tid & 15)*4;
      st4(&Ws[kk][c0], ld4(W + (size_t)(cb+kk)*HH + k0 + c0)); }
    __syncthreads();
    for (int kk = 0; kk < 16; ++kk){
      float a0 = As[ty*4+0][kk], a1 = As[ty*4+1][kk], a2 = As[ty*4+2][kk], a3 = As[ty*4+3][kk];
      float4 w = ld4(&Ws[kk][tx*4]);
      acc[0][0]+=a0*w.x; acc[0][1]+=a0*w.y; acc[0][2]+=a0*w.z; acc[0][3]+=a0*w.w;
      acc[1][0]+=a1*w.x; acc[1][1]+=a1*w.y; acc[1][2]+=a1*w.z; acc[1][3]+=a1*w.w;
      acc[2][0]+=a2*w.x; acc[2][1]+=a2*w.y; acc[2][2]+=a2*w.z; acc[2][3]+=a2*w.w;
      acc[3][0]+=a3*w.x; acc[3][1]+=a3*w.y; acc[3][2]+=a3*w.z; acc[3][3]+=a3*w.w;
    }
    __syncthreads();
  }
  #pragma unroll
  for (int i=0;i<4;++i)
    st4(Y + (size_t)(m0+ty*4+i)*HH + k0 + tx*4, make_float4(acc[i][0],acc[i][1],acc[i][2],acc[i][3]));
}

// partial softmax-weighted sums over l for dummy_c
__global__ __launch_bounds__(256) void k_dummy1(const float* __restrict__ Y, const float* __restrict__ gx2f,
    const int* __restrict__ mask, const float* __restrict__ c,
    float* __restrict__ pnum, float* __restrict__ pden){
  int b = blockIdx.x, ch = blockIdx.y, k = threadIdx.x;
  float gx = gx2f[b*HH+k];
  float num = 0.f, den = 0.f;
  int l0 = ch*128;
  for (int l = l0; l < l0+128; ++l){
    size_t idx = ((size_t)b*LL + l)*HH + k;
    float t = Y[idx] + gx;
    float s = sigm(t);
    float ms = (float)mask[b*LL+l]*1e25f - 1e25f;
    float e = expf(s + ms);
    num += e * c[idx]; den += e;
  }
  pnum[(size_t)(b*8+ch)*HH + k] = num;
  pden[(size_t)(b*8+ch)*HH + k] = den;
}

__global__ __launch_bounds__(256) void k_dummy2(const float* __restrict__ pnum, const float* __restrict__ pden,
    const float* __restrict__ g_d, const float* __restrict__ g_o, const float* __restrict__ dc,
    float* __restrict__ dh_n, float* __restrict__ dc_n){
  int b = blockIdx.x, k = threadIdx.x;
  float num = 0.f, den = 0.f;
  for (int ch = 0; ch < 8; ++ch){
    num += pnum[(size_t)(b*8+ch)*HH + k];
    den += pden[(size_t)(b*8+ch)*HH + k];
  }
  float ed = expf(g_d[b*HH+k]);
  float v = (num + ed*dc[b*HH+k])/(den + ed);
  dc_n[b*HH+k] = v;
  dh_n[b*HH+k] = g_o[b*HH+k]*tanhf(v);
}

// fused main GEMM: A=[h,hb,ha,emb] (K=1024), 7 gates, + full pointwise epilogue
__global__ __launch_bounds__(256) void k_main(const float* __restrict__ h, const float* __restrict__ c,
    const float* __restrict__ win, const int* __restrict__ mask,
    const float* __restrict__ Wx, const float* __restrict__ Wh, const float* __restrict__ Wi,
    const float* __restrict__ wd, const float* __restrict__ dc,
    float* __restrict__ hout, float* __restrict__ cout){
  __shared__ float As[64][17];
  __shared__ __align__(16) float Ws[NG][16][64];
  int m0 = blockIdx.x*64, k0 = blockIdx.y*64;
  int tid = threadIdx.x, tx = tid & 15, ty = tid >> 4;
  int b = m0 >> 10;  // whole 64-row tile is in one batch (1024 % 64 == 0)
  float acc[NG][4][4];
  #pragma unroll
  for (int g=0; g<NG; ++g)
    #pragma unroll
    for (int i=0;i<4;++i){ acc[g][i][0]=0.f; acc[g][i][1]=0.f; acc[g][i][2]=0.f; acc[g][i][3]=0.f; }

  for (int kc = 0; kc < 64; ++kc){
    int slice = kc >> 4;          // 0:h 1:hb 2:ha 3:emb
    int cb = (kc & 15) << 4;      // col base within slice
    { // A tile: 64 rows x 16 k
      int r = tid >> 2, c0 = (tid & 3) << 2;
      int m = m0 + r, l = m & (LL-1);
      float4 v;
      if (slice == 0) v = ld4(h + (size_t)m*HH + cb + c0);
      else if (slice == 1){
        v = f4z();
        if (l >= 1) v = f4add(v, ld4(h + (size_t)(m-1)*HH + cb + c0));
        if (l >= 2) v = f4add(v, ld4(h + (size_t)(m-2)*HH + cb + c0));
      } else if (slice == 2){
        v = f4z();
        if (l < LL-1) v = f4add(v, ld4(h + (size_t)(m+1)*HH + cb + c0));
        if (l < LL-2) v = f4add(v, ld4(h + (size_t)(m+2)*HH + cb + c0));
      } else {
        v = f4scale(ld4(win + (size_t)m*DD + cb + c0), (float)mask[m]);
      }
      As[r][c0+0]=v.x; As[r][c0+1]=v.y; As[r][c0+2]=v.z; As[r][c0+3]=v.w;
    }
    { // W tiles for all 7 gates: 16 k x 64 n each
      int kk = tid >> 4, c0 = (tid & 15) << 2;
      int row = cb + kk;
      #pragma unroll
      for (int g = 0; g < NG; ++g){
        const float* src;
        if (slice == 0)      src = Wx + (size_t)g*HW  + (size_t)row*HH       + k0 + c0;
        else if (slice == 1) src = Wh + (size_t)g*WhS + (size_t)row*HH       + k0 + c0;
        else if (slice == 2) src = Wh + (size_t)g*WhS + (size_t)(256+row)*HH + k0 + c0;
        else                 src = Wi + (size_t)g*HW  + (size_t)row*HH       + k0 + c0;
        st4(&Ws[g][kk][c0], ld4(src));
      }
    }
    __syncthreads();
    for (int kk = 0; kk < 16; ++kk){
      float a0 = As[ty*4+0][kk], a1 = As[ty*4+1][kk], a2 = As[ty*4+2][kk], a3 = As[ty*4+3][kk];
      #pragma unroll
      for (int g = 0; g < NG; ++g){
        float4 w = ld4(&Ws[g][kk][tx<<2]);
        acc[g][0][0]+=a0*w.x; acc[g][0][1]+=a0*w.y; acc[g][0][2]+=a0*w.z; acc[g][0][3]+=a0*w.w;
        acc[g][1][0]+=a1*w.x; acc[g][1][1]+=a1*w.y; acc[g][1][2]+=a1*w.z; acc[g][1][3]+=a1*w.w;
        acc[g][2][0]+=a2*w.x; acc[g][2][1]+=a2*w.y; acc[g][2][2]+=a2*w.z; acc[g][2][3]+=a2*w.w;
        acc[g][3][0]+=a3*w.x; acc[g][3][1]+=a3*w.y; acc[g][3][2]+=a3*w.z; acc[g][3][3]+=a3*w.w;
      }
    }
    __syncthreads();
  }

  // epilogue
  int col = k0 + (tx << 2);
  float wdv[NG][4];
  #pragma unroll
  for (int g=0; g<NG; ++g){
    float4 t = ld4(wd + (size_t)(g*BB + b)*HH + col);
    wdv[g][0]=t.x; wdv[g][1]=t.y; wdv[g][2]=t.z; wdv[g][3]=t.w;
  }
  float4 t_dc = ld4(dc + (size_t)b*HH + col);
  float dcv[4] = {t_dc.x, t_dc.y, t_dc.z, t_dc.w};

  #pragma unroll
  for (int i=0;i<4;++i){
    int m = m0 + ty*4 + i, l = m & (LL-1);
    float fm = (float)mask[m];
    float4 t_cc = ld4(c + (size_t)m*HH + col);
    float4 cb4 = f4z(), ca4 = f4z();
    if (l >= 1)    cb4 = f4add(cb4, ld4(c + (size_t)(m-1)*HH + col));
    if (l >= 2)    cb4 = f4add(cb4, ld4(c + (size_t)(m-2)*HH + col));
    if (l < LL-1)  ca4 = f4add(ca4, ld4(c + (size_t)(m+1)*HH + col));
    if (l < LL-2)  ca4 = f4add(ca4, ld4(c + (size_t)(m+2)*HH + col));
    float ccv[4] = {t_cc.x,t_cc.y,t_cc.z,t_cc.w};
    float cbv[4] = {cb4.x,cb4.y,cb4.z,cb4.w};
    float cav[4] = {ca4.x,ca4.y,ca4.z,ca4.w};
    float ho[4], co[4];
    #pragma unroll
    for (int j=0;j<4;++j){
      float s0 = sigm(acc[0][i][j] + wdv[0][j]);
      float s1 = sigm(acc[1][i][j] + wdv[1][j]);
      float s2 = sigm(acc[2][i][j] + wdv[2][j]);
      float s3 = sigm(acc[3][i][j] + wdv[3][j]);
      float s4 = sigm(acc[4][i][j] + wdv[4][j]);
      float s5 = sigm(acc[5][i][j] + wdv[5][j]);
      float u  = tanhf(acc[6][i][j] + wdv[6][j]);
      float mx = fmaxf(fmaxf(fmaxf(s0,s1),fmaxf(s2,s3)),s4);
      float e0 = expf(s0-mx), e1 = expf(s1-mx), e2 = expf(s2-mx), e3 = expf(s3-mx), e4 = expf(s4-mx);
      float inv = 1.0f/(e0+e1+e2+e3+e4);
      float cn = (e0*cbv[j] + e1*cav[j] + e2*ccv[j] + e3*dcv[j] + e4*u)*inv;
      float hn = s5*tanhf(cn);
      ho[j] = hn*fm; co[j] = cn*fm;
    }
    st4(hout + (size_t)m*HH + col, make_float4(ho[0],ho[1],ho[2],ho[3]));
    st4(cout + (size_t)m*HH + col, make_float4(co[0],co[1],co[2],co[3]));
  }
}

extern "C" void kernel_launch(void* const* d_in, const int* in_sizes, int n_in,
                              void* d_out, int out_size, void* d_ws, size_t ws_size,
                              hipStream_t stream) {
  const float* win   = (const float*)d_in[0];
  const int*   mask  = (const int*)d_in[1];
  // d_in[2] = num_layers (always 3 for this problem)
  const float* ih    = (const float*)d_in[3];
  const float* ic    = (const float*)d_in[4];
  const float* Wx    = (const float*)d_in[5];
  const float* Wh    = (const float*)d_in[6];
  const float* Wi    = (const float*)d_in[7];
  const float* Wd    = (const float*)d_in[8];
  const float* bias  = (const float*)d_in[9];
  const float* gWx   = (const float*)d_in[10];
  const float* gWh   = (const float*)d_in[11];
  const float* gb    = (const float*)d_in[12];

  const size_t SZ = (size_t)BB*LL*HH;   // 8388608 elements (32 MB f32)
  float* base = (float*)d_ws;
  float* hA = base;              // h buffer 0
  float* hB = (float*)d_out;     // h buffer 1 — d_out doubles as h storage;
                                 // with 3 layers the final h lands in d_out.
  float* cA = base + SZ;
  float* cB = base + 2*SZ;
  float* sm = base + 3*SZ;
  float* comb  = sm; sm += BB*HH;
  float* combc = sm; sm += BB*HH;
  float* dhb[2]; dhb[0] = sm; sm += BB*HH; dhb[1] = sm; sm += BB*HH;
  float* dcb[2]; dcb[0] = sm; sm += BB*HH; dcb[1] = sm; sm += BB*HH;
  float* g_d  = sm; sm += BB*HH;
  float* g_o  = sm; sm += BB*HH;
  float* gx2f = sm; sm += BB*HH;
  float* wd   = sm; sm += (size_t)NG*BB*HH;
  float* pnum = sm; sm += (size_t)BB*8*HH;
  float* pden = sm; sm += (size_t)BB*8*HH;

  k_init<<<2048, 256, 0, stream>>>(ih, ic, mask, hA, cA);

  float *h_cur = hA, *h_nxt = hB, *c_cur = cA, *c_nxt = cB;
  for (int layer = 0; layer < 3; ++layer){
    k_mean<<<BB, 256, 0, stream>>>(h_cur, c_cur, comb, combc);
    const float* dh_l = (layer == 0) ? comb  : dhb[(layer+1)&1];
    const float* dc_l = (layer == 0) ? combc : dcb[(layer+1)&1];
    k_small<<<BB, 256, 0, stream>>>(dh_l, comb, gWx, gWh, gb, Wd, bias, g_d, g_o, gx2f, wd);
    float* Y = h_nxt;  // alias: consumed by k_dummy1 before k_main overwrites
    k_gemm_gf<<<dim3(512,4), 256, 0, stream>>>(h_cur, gWh + 2*HW, Y);
    k_dummy1<<<dim3(BB,8), 256, 0, stream>>>(Y, gx2f, mask, c_cur, pnum, pden);
    k_dummy2<<<BB, 256, 0, stream>>>(pnum, pden, g_d, g_o, dc_l, dhb[layer&1], dcb[layer&1]);
    k_main<<<dim3(512,4), 256, 0, stream>>>(h_cur, c_cur, win, mask, Wx, Wh, Wi, wd, dc_l,
                                            h_nxt, c_nxt);
    float* t;
    t = h_cur; h_cur = h_nxt; h_nxt = t;
    t = c_cur; c_cur = c_nxt; c_nxt = t;
  }
  // after 3 swaps h_cur == hB == d_out: final h is already in d_out.
}

// Round 4
// 1634.896 us; speedup vs baseline: 4.1104x; 4.1104x over previous
//
#include <hip/hip_runtime.h>
#include <math.h>

#define BB 32
#define LL 1024
#define DD 256
#define HH 256
#define NG 7
#define HW (HH*HH)       /* 65536 */
#define WhS (2*HH*HH)    /* Wh per-gate stride */

typedef short bf16x8 __attribute__((ext_vector_type(8)));
typedef float f32x4  __attribute__((ext_vector_type(4)));
typedef unsigned short u16;

__device__ __forceinline__ float sigm(float x){ return 1.0f/(1.0f + expf(-x)); }
__device__ __forceinline__ u16 f2b(float f){
  unsigned int u = __float_as_uint(f);
  return (u16)((u + 0x7fffu + ((u>>16)&1u)) >> 16);   // RNE
}
__device__ __forceinline__ float b2f(u16 b){ return __uint_as_float(((unsigned int)b)<<16); }
__device__ __forceinline__ float4 ld4(const float* p){ return *reinterpret_cast<const float4*>(p); }

__device__ __forceinline__ void gload16(const void* g, void* l){
  __builtin_amdgcn_global_load_lds(
    (const __attribute__((address_space(1))) unsigned int*)g,
    (__attribute__((address_space(3))) unsigned int*)l, 16, 0, 0);
}
__device__ __forceinline__ f32x4 mfma16(bf16x8 a, bf16x8 b, f32x4 c){
  return __builtin_amdgcn_mfma_f32_16x16x32_bf16(a, b, c, 0, 0, 0);
}

// ---------------- init: h=(ih*0.1-0.05)*fm (bf16), c likewise (f32) ----------------
__global__ __launch_bounds__(256) void k_init(const float* __restrict__ ih, const float* __restrict__ ic,
    const int* __restrict__ mask, u16* __restrict__ h, float* __restrict__ c){
  size_t n = (size_t)BB*LL*HH;
  for (size_t idx = (size_t)blockIdx.x*256 + threadIdx.x; idx < n; idx += (size_t)gridDim.x*256){
    float fm = (float)mask[idx>>8];
    h[idx] = f2b((ih[idx]*0.1f - 0.05f)*fm);
    c[idx] = (ic[idx]*0.1f - 0.05f)*fm;
  }
}

// ---------------- mean over L ----------------
__global__ __launch_bounds__(256) void k_mean(const u16* __restrict__ h, const float* __restrict__ c,
    float* __restrict__ comb, float* __restrict__ combc){
  int b = blockIdx.x, k = threadIdx.x;
  const u16* hp = h + (size_t)b*LL*HH + k;
  const float* cp = c + (size_t)b*LL*HH + k;
  float sh = 0.f, sc = 0.f;
  for (int l = 0; l < LL; ++l){ sh += b2f(hp[(size_t)l*HH]); sc += cp[(size_t)l*HH]; }
  comb[b*HH+k]  = sh*(1.0f/LL);
  combc[b*HH+k] = sc*(1.0f/LL);
}

// ---------------- small (B,H) GEMMs ----------------
__global__ __launch_bounds__(256) void k_small(const float* __restrict__ dh, const float* __restrict__ comb,
    const float* __restrict__ gWx, const float* __restrict__ gWh, const float* __restrict__ gb,
    const float* __restrict__ Wd, const float* __restrict__ bias,
    float* __restrict__ g_d, float* __restrict__ g_o, float* __restrict__ gx2f, float* __restrict__ wd){
  __shared__ float dsh[HH], csh[HH];
  int b = blockIdx.x, k = threadIdx.x;
  dsh[k] = dh[b*HH+k]; csh[k] = comb[b*HH+k];
  __syncthreads();
  float ad = gb[0*HH+k], ao = gb[1*HH+k], ax = gb[2*HH+k];
  for (int j = 0; j < HH; ++j){
    float dv = dsh[j], cv = csh[j];
    ad += dv*gWx[j*HH+k]      + cv*gWh[j*HH+k];
    ao += dv*gWx[HW + j*HH+k] + cv*gWh[HW + j*HH+k];
    ax += dv*gWx[2*HW + j*HH+k];
  }
  g_d[b*HH+k] = sigm(ad);
  g_o[b*HH+k] = sigm(ao);
  gx2f[b*HH+k] = ax;
  for (int g = 0; g < NG; ++g){
    float aw = bias[g*HH+k];
    const float* W = Wd + (size_t)g*HW + k;
    for (int j = 0; j < HH; ++j) aw += dsh[j]*W[(size_t)j*HH];
    wd[(size_t)(g*BB + b)*HH + k] = aw;
  }
}

// ---------------- weight pack: swizzled LDS images ----------------
// Bp element idx: img=idx/14336 (img=nt*32+ks), e=idx%14336:
//   g=e>>11, n=(e>>5)&63, s=(e>>3)&3, j=e&7, kblk=s^((n>>1)&3)
//   K=ks*32+kblk*8+j, N=nt*64+n; slice=K>>8 selects Wx/Wh(top)/Wh(bot)/Wi
__global__ __launch_bounds__(256) void k_wpack(const float* __restrict__ Wx, const float* __restrict__ Wh,
    const float* __restrict__ Wi, u16* __restrict__ Bp){
  int idx = blockIdx.x*256 + threadIdx.x;      // 0..1835007
  int img = idx / 14336, e = idx % 14336;
  int nt = img >> 5, ks = img & 31;
  int g = e >> 11, n = (e>>5)&63, s = (e>>3)&3, j = e&7;
  int kblk = s ^ ((n>>1)&3);
  int K = ks*32 + kblk*8 + j;
  int N = nt*64 + n;
  int slice = K >> 8, kr = K & 255;
  float v;
  if (slice == 0)      v = Wx[(size_t)g*HW  + (size_t)kr*HH + N];
  else if (slice == 1) v = Wh[(size_t)g*WhS + (size_t)kr*HH + N];
  else if (slice == 2) v = Wh[(size_t)g*WhS + (size_t)(256+kr)*HH + N];
  else                 v = Wi[(size_t)g*HW  + (size_t)kr*HH + N];
  Bp[idx] = f2b(v);
}

__global__ __launch_bounds__(256) void k_gw2pack(const float* __restrict__ gWh, u16* __restrict__ Gp){
  int idx = blockIdx.x*256 + threadIdx.x;      // 0..65535
  int img = idx >> 11, e = idx & 2047;         // img=nt*8+ks
  int nt = img >> 3, ks = img & 7;
  int n = (e>>5)&63, s = (e>>3)&3, j = e&7;
  int kblk = s ^ ((n>>1)&3);
  int K = ks*32 + kblk*8 + j, N = nt*64 + n;
  Gp[idx] = f2b(gWh[2*HW + (size_t)K*HH + N]);
}

// ---------------- g_f GEMM + masked-exp partial sums (fused, deterministic) ----------------
__global__ __launch_bounds__(256) void k_gf(const u16* __restrict__ h, const u16* __restrict__ Gp,
    const float* __restrict__ gx2f, const int* __restrict__ mask, const float* __restrict__ c,
    float* __restrict__ pnumP, float* __restrict__ pdenP){
  __shared__ __align__(16) unsigned char lsA[4096];
  __shared__ __align__(16) unsigned char lsB[4096];
  __shared__ float redN[2][4][64], redD[2][4][64];
  int tid = threadIdx.x, lane = tid & 63, wid = tid >> 6;
  int wm = wid >> 1, wn = wid & 1;
  int m0 = blockIdx.x*64, nt = blockIdx.y;
  int b = m0 >> 10;
  int rA = wid*16 + (lane>>2);
  int kbA = (lane&3) ^ ((rA>>1)&3);
  f32x4 acc[2][2];
  #pragma unroll
  for (int i=0;i<2;++i){ acc[i][0] = (f32x4)0.f; acc[i][1] = (f32x4)0.f; }

  for (int ks = 0; ks < 8; ++ks){
    int cb = ks*32;
    __syncthreads();
    gload16(h + (size_t)(m0+rA)*HH + cb + kbA*8, lsA + wid*1024);
    gload16((const unsigned char*)Gp + (size_t)(nt*8+ks)*4096 + wid*1024 + (size_t)lane*16,
            lsB + wid*1024);
    __syncthreads();
    int li = lane & 15, kg = lane >> 4;
    int r0 = wm*32 + li, r1 = r0 + 16;
    int n0 = wn*32 + li, n1 = n0 + 16;
    bf16x8 a0 = *(const bf16x8*)(lsA + r0*64 + ((kg ^ ((r0>>1)&3))<<4));
    bf16x8 a1 = *(const bf16x8*)(lsA + r1*64 + ((kg ^ ((r1>>1)&3))<<4));
    bf16x8 b0 = *(const bf16x8*)(lsB + n0*64 + ((kg ^ ((n0>>1)&3))<<4));
    bf16x8 b1 = *(const bf16x8*)(lsB + n1*64 + ((kg ^ ((n1>>1)&3))<<4));
    acc[0][0] = mfma16(a0, b0, acc[0][0]);
    acc[0][1] = mfma16(a0, b1, acc[0][1]);
    acc[1][0] = mfma16(a1, b0, acc[1][0]);
    acc[1][1] = mfma16(a1, b1, acc[1][1]);
  }

  int li = lane & 15, lg = lane >> 4;
  float gx[2], sn[2] = {0.f,0.f}, sd[2] = {0.f,0.f};
  int colg[2];
  #pragma unroll
  for (int nf=0; nf<2; ++nf){
    colg[nf] = nt*64 + wn*32 + nf*16 + li;
    gx[nf] = gx2f[b*HH + colg[nf]];
  }
  #pragma unroll
  for (int mf=0; mf<2; ++mf)
  #pragma unroll
  for (int j=0; j<4; ++j){
    int m = m0 + wm*32 + mf*16 + lg*4 + j;
    int msk = mask[m];
    #pragma unroll
    for (int nf=0; nf<2; ++nf){
      float s = sigm(acc[mf][nf][j] + gx[nf]);
      float e = msk ? expf(s) : 0.0f;
      sn[nf] += e * c[(size_t)m*HH + colg[nf]];
      sd[nf] += e;
    }
  }
  #pragma unroll
  for (int nf=0; nf<2; ++nf){
    redN[wm][lg][wn*32 + nf*16 + li] = sn[nf];
    redD[wm][lg][wn*32 + nf*16 + li] = sd[nf];
  }
  __syncthreads();
  if (tid < 64){
    float n = 0.f, d = 0.f;
    #pragma unroll
    for (int w2=0; w2<2; ++w2)
      #pragma unroll
      for (int l2=0; l2<4; ++l2){ n += redN[w2][l2][tid]; d += redD[w2][l2][tid]; }
    pnumP[(size_t)blockIdx.x*HH + nt*64 + tid] = n;
    pdenP[(size_t)blockIdx.x*HH + nt*64 + tid] = d;
  }
}

__global__ __launch_bounds__(256) void k_dummy2(const float* __restrict__ pnumP, const float* __restrict__ pdenP,
    const float* __restrict__ g_d, const float* __restrict__ g_o, const float* __restrict__ dc,
    float* __restrict__ dh_n, float* __restrict__ dc_n){
  int b = blockIdx.x, k = threadIdx.x;
  float num = 0.f, den = 0.f;
  for (int mt = 0; mt < 16; ++mt){
    num += pnumP[(size_t)(b*16+mt)*HH + k];
    den += pdenP[(size_t)(b*16+mt)*HH + k];
  }
  float ed = expf(g_d[b*HH+k]);
  float v = (num + ed*dc[b*HH+k])/(den + ed);
  dc_n[b*HH+k] = v;
  dh_n[b*HH+k] = g_o[b*HH+k]*tanhf(v);
}

// ---------------- main fused MFMA GEMM + epilogue ----------------
// block: 64 rows x (7 gates x 64 cols); 4 waves 2x2; K=1024 in 32 steps of 32
__global__ __launch_bounds__(256) void k_main(const u16* __restrict__ h, const float* __restrict__ c,
    const float* __restrict__ win, const int* __restrict__ mask, const u16* __restrict__ Bp,
    const float* __restrict__ wd, const float* __restrict__ dc,
    u16* __restrict__ hout, float* __restrict__ cout, float* __restrict__ hf32,
    int wf32, int wc){
  __shared__ __align__(16) unsigned char lsA[4096];
  __shared__ __align__(16) unsigned char lsB[28672];
  int tid = threadIdx.x, lane = tid & 63, wid = tid >> 6;
  int wm = wid >> 1, wn = wid & 1;
  int m0 = blockIdx.x*64, nt = blockIdx.y;
  int b = m0 >> 10;
  int rA = wid*16 + (lane>>2);
  int kbA = (lane&3) ^ ((rA>>1)&3);
  int mA = m0 + rA, lpA = mA & (LL-1);
  unsigned char* dstA = lsA + wid*1024 + lane*16;  // per-lane (ds_write path)

  f32x4 acc[NG][2][2];
  #pragma unroll
  for (int g=0; g<NG; ++g)
    #pragma unroll
    for (int i=0; i<2; ++i){ acc[g][i][0] = (f32x4)0.f; acc[g][i][1] = (f32x4)0.f; }

  for (int ks = 0; ks < 32; ++ks){
    int slice = ks >> 3, cb = (ks & 7)*32;
    int co = cb + kbA*8;
    __syncthreads();
    { // stage B: 7 gates, linear copy of pre-swizzled image
      const unsigned char* bs = (const unsigned char*)Bp + (size_t)(nt*32+ks)*28672;
      #pragma unroll
      for (int g = 0; g < NG; ++g)
        gload16(bs + (size_t)(g*4+wid)*1024 + (size_t)lane*16, lsB + (g*4+wid)*1024);
    }
    // stage A
    if (slice == 0){
      gload16(h + (size_t)mA*HH + co, lsA + wid*1024);
    } else if (slice == 1){          // hb = h[l-1]+h[l-2]
      float f[8] = {0,0,0,0,0,0,0,0};
      if (lpA >= 1){ bf16x8 a = *(const bf16x8*)(h + (size_t)(mA-1)*HH + co);
        #pragma unroll
        for (int j=0;j<8;++j) f[j] += b2f((u16)a[j]); }
      if (lpA >= 2){ bf16x8 a = *(const bf16x8*)(h + (size_t)(mA-2)*HH + co);
        #pragma unroll
        for (int j=0;j<8;++j) f[j] += b2f((u16)a[j]); }
      bf16x8 v;
      #pragma unroll
      for (int j=0;j<8;++j) v[j] = (short)f2b(f[j]);
      *(bf16x8*)dstA = v;
    } else if (slice == 2){          // ha = h[l+1]+h[l+2]
      float f[8] = {0,0,0,0,0,0,0,0};
      if (lpA <= LL-2){ bf16x8 a = *(const bf16x8*)(h + (size_t)(mA+1)*HH + co);
        #pragma unroll
        for (int j=0;j<8;++j) f[j] += b2f((u16)a[j]); }
      if (lpA <= LL-3){ bf16x8 a = *(const bf16x8*)(h + (size_t)(mA+2)*HH + co);
        #pragma unroll
        for (int j=0;j<8;++j) f[j] += b2f((u16)a[j]); }
      bf16x8 v;
      #pragma unroll
      for (int j=0;j<8;++j) v[j] = (short)f2b(f[j]);
      *(bf16x8*)dstA = v;
    } else {                          // emb = win*mask
      float fm = (float)mask[mA];
      float4 w0 = ld4(win + (size_t)mA*DD + co);
      float4 w1 = ld4(win + (size_t)mA*DD + co + 4);
      bf16x8 v;
      v[0]=(short)f2b(w0.x*fm); v[1]=(short)f2b(w0.y*fm); v[2]=(short)f2b(w0.z*fm); v[3]=(short)f2b(w0.w*fm);
      v[4]=(short)f2b(w1.x*fm); v[5]=(short)f2b(w1.y*fm); v[6]=(short)f2b(w1.z*fm); v[7]=(short)f2b(w1.w*fm);
      *(bf16x8*)dstA = v;
    }
    __syncthreads();
    // compute
    int li = lane & 15, kg = lane >> 4;
    int r0 = wm*32 + li, r1 = r0 + 16;
    int n0 = wn*32 + li, n1 = n0 + 16;
    bf16x8 a0 = *(const bf16x8*)(lsA + r0*64 + ((kg ^ ((r0>>1)&3))<<4));
    bf16x8 a1 = *(const bf16x8*)(lsA + r1*64 + ((kg ^ ((r1>>1)&3))<<4));
    int ob0 = n0*64 + ((kg ^ ((n0>>1)&3))<<4);
    int ob1 = n1*64 + ((kg ^ ((n1>>1)&3))<<4);
    #pragma unroll
    for (int g = 0; g < NG; ++g){
      bf16x8 b0 = *(const bf16x8*)(lsB + g*4096 + ob0);
      bf16x8 b1 = *(const bf16x8*)(lsB + g*4096 + ob1);
      acc[g][0][0] = mfma16(a0, b0, acc[g][0][0]);
      acc[g][0][1] = mfma16(a0, b1, acc[g][0][1]);
      acc[g][1][0] = mfma16(a1, b0, acc[g][1][0]);
      acc[g][1][1] = mfma16(a1, b1, acc[g][1][1]);
    }
  }

  // epilogue
  int li = lane & 15, lg = lane >> 4;
  int colg[2]; float wdv[NG][2], dcv[2];
  #pragma unroll
  for (int nf=0; nf<2; ++nf){
    colg[nf] = nt*64 + wn*32 + nf*16 + li;
    dcv[nf] = dc[b*HH + colg[nf]];
    #pragma unroll
    for (int g=0; g<NG; ++g) wdv[g][nf] = wd[(size_t)(g*BB+b)*HH + colg[nf]];
  }
  #pragma unroll
  for (int mf=0; mf<2; ++mf)
  #pragma unroll
  for (int j=0; j<4; ++j){
    int m = m0 + wm*32 + mf*16 + lg*4 + j;
    int lp = m & (LL-1);
    float fm = (float)mask[m];
    #pragma unroll
    for (int nf=0; nf<2; ++nf){
      int col = colg[nf];
      const float* cp = c + (size_t)m*HH + col;
      float cc = cp[0];
      float cbv = 0.f, cav = 0.f;
      if (lp >= 1)    cbv += cp[-(int)HH];
      if (lp >= 2)    cbv += cp[-2*(int)HH];
      if (lp <= LL-2) cav += cp[HH];
      if (lp <= LL-3) cav += cp[2*HH];
      float s0 = sigm(acc[0][mf][nf][j] + wdv[0][nf]);
      float s1 = sigm(acc[1][mf][nf][j] + wdv[1][nf]);
      float s2 = sigm(acc[2][mf][nf][j] + wdv[2][nf]);
      float s3 = sigm(acc[3][mf][nf][j] + wdv[3][nf]);
      float s4 = sigm(acc[4][mf][nf][j] + wdv[4][nf]);
      float s5 = sigm(acc[5][mf][nf][j] + wdv[5][nf]);
      float u  = tanhf(acc[6][mf][nf][j] + wdv[6][nf]);
      float mx = fmaxf(fmaxf(fmaxf(s0,s1),fmaxf(s2,s3)),s4);
      float e0 = expf(s0-mx), e1 = expf(s1-mx), e2 = expf(s2-mx), e3 = expf(s3-mx), e4 = expf(s4-mx);
      float inv = 1.0f/(e0+e1+e2+e3+e4);
      float cn = (e0*cbv + e1*cav + e2*cc + e3*dcv[nf] + e4*u)*inv;
      float hn = s5*tanhf(cn);
      hout[(size_t)m*HH + col] = f2b(hn*fm);
      if (wc)   cout[(size_t)m*HH + col] = cn*fm;
      if (wf32) hf32[(size_t)m*HH + col] = hn*fm;
    }
  }
}

extern "C" void kernel_launch(void* const* d_in, const int* in_sizes, int n_in,
                              void* d_out, int out_size, void* d_ws, size_t ws_size,
                              hipStream_t stream) {
  const float* win   = (const float*)d_in[0];
  const int*   mask  = (const int*)d_in[1];
  // d_in[2] = num_layers (always 3)
  const float* ih    = (const float*)d_in[3];
  const float* ic    = (const float*)d_in[4];
  const float* Wx    = (const float*)d_in[5];
  const float* Wh    = (const float*)d_in[6];
  const float* Wi    = (const float*)d_in[7];
  const float* Wd    = (const float*)d_in[8];
  const float* bias  = (const float*)d_in[9];
  const float* gWx   = (const float*)d_in[10];
  const float* gWh   = (const float*)d_in[11];
  const float* gb    = (const float*)d_in[12];

  const size_t SZ = (size_t)BB*LL*HH;   // 8388608
  char* p = (char*)d_ws;
  auto alloc = [&](size_t bytes)->char*{ char* r = p; p += (bytes + 255) & ~(size_t)255; return r; };
  u16*   hA    = (u16*)  alloc(SZ*2);            // 16MB  h state (bf16), dbuf
  u16*   hB    = (u16*)  alloc(SZ*2);            // 16MB
  float* cA    = (float*)alloc(SZ*4);            // 32MB  c state (f32)
  float* cB    = (float*)d_out;                  // d_out doubles as 2nd c buffer (L0 write, L1 read)
  u16*   Bp    = (u16*)  alloc((size_t)1835008*2);  // 3.5MB packed gate weights
  u16*   Gp    = (u16*)  alloc((size_t)65536*2);    // 128KB packed gWh[2]
  float* comb  = (float*)alloc(BB*HH*4);
  float* combc = (float*)alloc(BB*HH*4);
  float* dh0   = (float*)alloc(BB*HH*4);
  float* dh1   = (float*)alloc(BB*HH*4);
  float* dc0   = (float*)alloc(BB*HH*4);
  float* dc1   = (float*)alloc(BB*HH*4);
  float* g_d   = (float*)alloc(BB*HH*4);
  float* g_o   = (float*)alloc(BB*HH*4);
  float* gx2f  = (float*)alloc(BB*HH*4);
  float* wd    = (float*)alloc((size_t)NG*BB*HH*4);
  float* pnumP = (float*)alloc((size_t)512*HH*4);  // per-M-tile partials (deterministic)
  float* pdenP = (float*)alloc((size_t)512*HH*4);
  float* dhb[2] = {dh0, dh1};
  float* dcb[2] = {dc0, dc1};

  k_wpack<<<7168, 256, 0, stream>>>(Wx, Wh, Wi, Bp);
  k_gw2pack<<<256, 256, 0, stream>>>(gWh, Gp);
  k_init<<<2048, 256, 0, stream>>>(ih, ic, mask, hA, cA);

  u16 *h_cur = hA, *h_nxt = hB;
  float *c_cur = cA, *c_nxt = cB;
  for (int layer = 0; layer < 3; ++layer){
    k_mean<<<BB, 256, 0, stream>>>(h_cur, c_cur, comb, combc);
    const float* dh_l = (layer == 0) ? comb  : dhb[(layer+1)&1];
    const float* dc_l = (layer == 0) ? combc : dcb[(layer+1)&1];
    k_small<<<BB, 256, 0, stream>>>(dh_l, comb, gWx, gWh, gb, Wd, bias, g_d, g_o, gx2f, wd);
    k_gf<<<dim3(512,4), 256, 0, stream>>>(h_cur, Gp, gx2f, mask, c_cur, pnumP, pdenP);
    k_dummy2<<<BB, 256, 0, stream>>>(pnumP, pdenP, g_d, g_o, dc_l, dhb[layer&1], dcb[layer&1]);
    int last = (layer == 2);
    k_main<<<dim3(512,4), 256, 0, stream>>>(h_cur, c_cur, win, mask, Bp, wd, dc_l,
                                            h_nxt, c_nxt, (float*)d_out, last, !last);
    u16* th = h_cur; h_cur = h_nxt; h_nxt = th;
    float* tc = c_cur; c_cur = c_nxt; c_nxt = tc;
  }
}

// Round 5
// 849.534 us; speedup vs baseline: 7.9103x; 1.9245x over previous
//
#include <hip/hip_runtime.h>
#include <math.h>

#define BB 32
#define LL 1024
#define DD 256
#define HH 256
#define NG 7
#define HW (HH*HH)       /* 65536 */
#define WhS (2*HH*HH)    /* Wh per-gate stride */

typedef short bf16x8 __attribute__((ext_vector_type(8)));
typedef float f32x4  __attribute__((ext_vector_type(4)));
typedef unsigned short u16;

__device__ __forceinline__ float sigm(float x){ return 1.0f/(1.0f + expf(-x)); }
__device__ __forceinline__ u16 f2b(float f){
  unsigned int u = __float_as_uint(f);
  return (u16)((u + 0x7fffu + ((u>>16)&1u)) >> 16);   // RNE
}
__device__ __forceinline__ float b2f(u16 b){ return __uint_as_float(((unsigned int)b)<<16); }
__device__ __forceinline__ float4 ld4(const float* p){ return *reinterpret_cast<const float4*>(p); }

__device__ __forceinline__ void gload16(const void* g, void* l){
  __builtin_amdgcn_global_load_lds(
    (const __attribute__((address_space(1))) unsigned int*)g,
    (__attribute__((address_space(3))) unsigned int*)l, 16, 0, 0);
}
__device__ __forceinline__ f32x4 mfma16(bf16x8 a, bf16x8 b, f32x4 c){
  return __builtin_amdgcn_mfma_f32_16x16x32_bf16(a, b, c, 0, 0, 0);
}

// ---------------- init ----------------
__global__ __launch_bounds__(256) void k_init(const float* __restrict__ ih, const float* __restrict__ ic,
    const int* __restrict__ mask, u16* __restrict__ h, float* __restrict__ c){
  size_t n = (size_t)BB*LL*HH;
  for (size_t idx = (size_t)blockIdx.x*256 + threadIdx.x; idx < n; idx += (size_t)gridDim.x*256){
    float fm = (float)mask[idx>>8];
    h[idx] = f2b((ih[idx]*0.1f - 0.05f)*fm);
    c[idx] = (ic[idx]*0.1f - 0.05f)*fm;
  }
}

// ---------------- mean over L: 2-stage ----------------
__global__ __launch_bounds__(256) void k_mean1(const u16* __restrict__ h, const float* __restrict__ c,
    float* __restrict__ pmh, float* __restrict__ pmc){
  int b = blockIdx.x, ch = blockIdx.y, k = threadIdx.x;
  const u16* hp = h + ((size_t)b*LL + ch*64)*HH + k;
  const float* cp = c + ((size_t)b*LL + ch*64)*HH + k;
  float sh = 0.f, sc = 0.f;
  for (int l = 0; l < 64; ++l){ sh += b2f(hp[(size_t)l*HH]); sc += cp[(size_t)l*HH]; }
  pmh[(size_t)(b*16+ch)*HH + k] = sh;
  pmc[(size_t)(b*16+ch)*HH + k] = sc;
}
__global__ __launch_bounds__(256) void k_mean2(const float* __restrict__ pmh, const float* __restrict__ pmc,
    float* __restrict__ comb, float* __restrict__ combc){
  int b = blockIdx.x, k = threadIdx.x;
  float sh = 0.f, sc = 0.f;
  for (int ch = 0; ch < 16; ++ch){
    sh += pmh[(size_t)(b*16+ch)*HH + k];
    sc += pmc[(size_t)(b*16+ch)*HH + k];
  }
  comb[b*HH+k]  = sh*(1.0f/LL);
  combc[b*HH+k] = sc*(1.0f/LL);
}

// ---------------- small (B,H) GEMMs, grid (BB, 8) ----------------
__global__ __launch_bounds__(256) void k_small(const float* __restrict__ dh, const float* __restrict__ comb,
    const float* __restrict__ gWx, const float* __restrict__ gWh, const float* __restrict__ gb,
    const float* __restrict__ Wd, const float* __restrict__ bias,
    float* __restrict__ g_d, float* __restrict__ g_o, float* __restrict__ gx2f, float* __restrict__ wd){
  __shared__ float dsh[HH], csh[HH];
  int b = blockIdx.x, g = blockIdx.y, k = threadIdx.x;
  dsh[k] = dh[b*HH+k]; csh[k] = comb[b*HH+k];
  __syncthreads();
  if (g < NG){
    float aw = bias[g*HH+k];
    const float* W = Wd + (size_t)g*HW + k;
    for (int j = 0; j < HH; ++j) aw += dsh[j]*W[(size_t)j*HH];
    wd[(size_t)(g*BB + b)*HH + k] = aw;
  } else {
    float ad = gb[0*HH+k], ao = gb[1*HH+k], ax = gb[2*HH+k];
    for (int j = 0; j < HH; ++j){
      float dv = dsh[j], cv = csh[j];
      ad += dv*gWx[j*HH+k]      + cv*gWh[j*HH+k];
      ao += dv*gWx[HW + j*HH+k] + cv*gWh[HW + j*HH+k];
      ax += dv*gWx[2*HW + j*HH+k];
    }
    g_d[b*HH+k] = sigm(ad);
    g_o[b*HH+k] = sigm(ao);
    gx2f[b*HH+k] = ax;
  }
}

// ---------------- weight pack (unchanged layout) ----------------
__global__ __launch_bounds__(256) void k_wpack(const float* __restrict__ Wx, const float* __restrict__ Wh,
    const float* __restrict__ Wi, u16* __restrict__ Bp){
  int idx = blockIdx.x*256 + threadIdx.x;      // 0..1835007
  int img = idx / 14336, e = idx % 14336;
  int nt = img >> 5, ks = img & 31;
  int g = e >> 11, n = (e>>5)&63, s = (e>>3)&3, j = e&7;
  int kblk = s ^ ((n>>1)&3);
  int K = ks*32 + kblk*8 + j;
  int N = nt*64 + n;
  int slice = K >> 8, kr = K & 255;
  float v;
  if (slice == 0)      v = Wx[(size_t)g*HW  + (size_t)kr*HH + N];
  else if (slice == 1) v = Wh[(size_t)g*WhS + (size_t)kr*HH + N];
  else if (slice == 2) v = Wh[(size_t)g*WhS + (size_t)(256+kr)*HH + N];
  else                 v = Wi[(size_t)g*HW  + (size_t)kr*HH + N];
  Bp[idx] = f2b(v);
}

__global__ __launch_bounds__(256) void k_gw2pack(const float* __restrict__ gWh, u16* __restrict__ Gp){
  int idx = blockIdx.x*256 + threadIdx.x;      // 0..65535
  int img = idx >> 11, e = idx & 2047;         // img=nt*8+ks
  int nt = img >> 3, ks = img & 7;
  int n = (e>>5)&63, s = (e>>3)&3, j = e&7;
  int kblk = s ^ ((n>>1)&3);
  int K = ks*32 + kblk*8 + j, N = nt*64 + n;
  Gp[idx] = f2b(gWh[2*HW + (size_t)K*HH + N]);
}

__global__ __launch_bounds__(256) void k_dummy2(const float* __restrict__ pnumP, const float* __restrict__ pdenP,
    const float* __restrict__ g_d, const float* __restrict__ g_o, const float* __restrict__ dc,
    float* __restrict__ dh_n, float* __restrict__ dc_n){
  int b = blockIdx.x, k = threadIdx.x;
  float num = 0.f, den = 0.f;
  for (int mt = 0; mt < 16; ++mt){
    num += pnumP[(size_t)(b*16+mt)*HH + k];
    den += pdenP[(size_t)(b*16+mt)*HH + k];
  }
  float ed = expf(g_d[b*HH+k]);
  float v = (num + ed*dc[b*HH+k])/(den + ed);
  dc_n[b*HH+k] = v;
  dh_n[b*HH+k] = g_o[b*HH+k]*tanhf(v);
}

// ---------------- main fused MFMA GEMM (7 gates + g_f) + epilogue ----------------
// 64 rows x (7x64 cols) per block; 4 waves, wave w: all 64 rows x 16 cols.
// 2-phase pipeline: prefetch K-step t+1 while computing t; one barrier/step.
__global__ __launch_bounds__(256, 2) void k_main(const u16* __restrict__ h, const float* __restrict__ c,
    const float* __restrict__ win, const int* __restrict__ mask, const u16* __restrict__ Bp,
    const u16* __restrict__ Gp, const float* __restrict__ wd, const float* __restrict__ dc,
    const float* __restrict__ gx2f,
    u16* __restrict__ hout, float* __restrict__ cout, float* __restrict__ hf32,
    float* __restrict__ pnumP, float* __restrict__ pdenP, int wf32, int wc){
  __shared__ __align__(16) unsigned char lsA[2][4096];
  __shared__ __align__(16) unsigned char lsB[2][NG*4096];
  __shared__ __align__(16) unsigned char lsB8[2][4096];

  int tid = threadIdx.x, lane = tid & 63, wid = tid >> 6;
  int flat = blockIdx.x;
  int swz = (flat & 7)*256 + (flat >> 3);      // XCD-bijective (2048 = 8*256)
  int nt = swz & 3, m0 = (swz >> 2) << 6;
  int b = m0 >> 10;
  int li = lane & 15, kg = lane >> 4;

  // A staging geometry (write side)
  int rA = wid*16 + (lane>>2);
  int kbA = (lane&3) ^ ((rA>>1)&3);
  int mA = m0 + rA, lpA = mA & (LL-1);

  // read-side offsets
  int nB = wid*16 + li;
  int obN = nB*64 + ((kg ^ ((nB>>1)&3))<<4);   // B-frag byte offset within a gate plane

  f32x4 acc[NG][4];
  f32x4 acc8[4];
  #pragma unroll
  for (int g=0; g<NG; ++g)
    #pragma unroll
    for (int mf=0; mf<4; ++mf) acc[g][mf] = (f32x4)0.f;
  #pragma unroll
  for (int mf=0; mf<4; ++mf) acc8[mf] = (f32x4)0.f;

  // ---- prologue: stage ks=0 (slice 0: all global_load_lds) ----
  {
    const unsigned char* bs = (const unsigned char*)Bp + (size_t)(nt*32+0)*28672;
    #pragma unroll
    for (int g = 0; g < NG; ++g)
      gload16(bs + (size_t)(g*4096 + wid*1024 + lane*16), lsB[0] + g*4096 + wid*1024);
    gload16((const unsigned char*)Gp + (size_t)(nt*8+0)*4096 + wid*1024 + (size_t)lane*16,
            lsB8[0] + wid*1024);
    gload16(h + (size_t)mA*HH + 0 + kbA*8, lsA[0] + wid*1024);
  }
  __syncthreads();

  int cur = 0;
  for (int ks = 0; ks < 32; ++ks){
    int nxt = cur ^ 1;
    // ---- prefetch ks+1 ----
    bool pend = false;
    float pf[8];
    if (ks < 31){
      int kn = ks + 1;
      int s1 = kn >> 3, cb1 = (kn & 7)*32, co1 = cb1 + kbA*8;
      const unsigned char* bs = (const unsigned char*)Bp + (size_t)(nt*32+kn)*28672;
      #pragma unroll
      for (int g = 0; g < NG; ++g)
        gload16(bs + (size_t)(g*4096 + wid*1024 + lane*16), lsB[nxt] + g*4096 + wid*1024);
      if (kn < 8)
        gload16((const unsigned char*)Gp + (size_t)(nt*8+kn)*4096 + wid*1024 + (size_t)lane*16,
                lsB8[nxt] + wid*1024);
      if (s1 == 0){
        gload16(h + (size_t)mA*HH + co1, lsA[nxt] + wid*1024);
      } else if (s1 == 1){
        pend = true;
        #pragma unroll
        for (int j=0;j<8;++j) pf[j] = 0.f;
        const u16* hp = h + (size_t)mA*HH + co1;
        if (lpA >= 1){ bf16x8 a = *(const bf16x8*)(hp - HH);
          #pragma unroll
          for (int j=0;j<8;++j) pf[j] += b2f((u16)a[j]); }
        if (lpA >= 2){ bf16x8 a = *(const bf16x8*)(hp - 2*HH);
          #pragma unroll
          for (int j=0;j<8;++j) pf[j] += b2f((u16)a[j]); }
      } else if (s1 == 2){
        pend = true;
        #pragma unroll
        for (int j=0;j<8;++j) pf[j] = 0.f;
        const u16* hp = h + (size_t)mA*HH + co1;
        if (lpA <= LL-2){ bf16x8 a = *(const bf16x8*)(hp + HH);
          #pragma unroll
          for (int j=0;j<8;++j) pf[j] += b2f((u16)a[j]); }
        if (lpA <= LL-3){ bf16x8 a = *(const bf16x8*)(hp + 2*HH);
          #pragma unroll
          for (int j=0;j<8;++j) pf[j] += b2f((u16)a[j]); }
      } else {
        pend = true;
        float fm = (float)mask[mA];
        float4 w0 = ld4(win + (size_t)mA*DD + co1);
        float4 w1 = ld4(win + (size_t)mA*DD + co1 + 4);
        pf[0]=w0.x*fm; pf[1]=w0.y*fm; pf[2]=w0.z*fm; pf[3]=w0.w*fm;
        pf[4]=w1.x*fm; pf[5]=w1.y*fm; pf[6]=w1.z*fm; pf[7]=w1.w*fm;
      }
    }
    // ---- compute current ----
    bf16x8 aa[4];
    #pragma unroll
    for (int mf=0; mf<4; ++mf){
      int r = mf*16 + li;
      aa[mf] = *(const bf16x8*)(lsA[cur] + r*64 + ((kg ^ ((r>>1)&3))<<4));
    }
    __builtin_amdgcn_s_setprio(1);
    #pragma unroll
    for (int g = 0; g < NG; ++g){
      bf16x8 bg = *(const bf16x8*)(lsB[cur] + g*4096 + obN);
      #pragma unroll
      for (int mf=0; mf<4; ++mf) acc[g][mf] = mfma16(aa[mf], bg, acc[g][mf]);
    }
    if (ks < 8){
      bf16x8 b8 = *(const bf16x8*)(lsB8[cur] + obN);
      #pragma unroll
      for (int mf=0; mf<4; ++mf) acc8[mf] = mfma16(aa[mf], b8, acc8[mf]);
    }
    __builtin_amdgcn_s_setprio(0);
    // ---- write reg-staged A, close the step ----
    if (ks < 31){
      if (pend){
        bf16x8 v;
        #pragma unroll
        for (int j=0;j<8;++j) v[j] = (short)f2b(pf[j]);
        *(bf16x8*)(lsA[nxt] + wid*1024 + lane*16) = v;
      }
      __syncthreads();
      cur = nxt;
    }
  }

  // ---- epilogue ----
  int col = nt*64 + wid*16 + li;
  float wdv[NG];
  #pragma unroll
  for (int g=0; g<NG; ++g) wdv[g] = wd[(size_t)(g*BB+b)*HH + col];
  float dcv = dc[b*HH + col];
  float gx  = gx2f[b*HH + col];
  float num = 0.f, den = 0.f;

  #pragma unroll
  for (int mf=0; mf<4; ++mf)
  #pragma unroll
  for (int j=0; j<4; ++j){
    int m = m0 + mf*16 + kg*4 + j;
    int lp = m & (LL-1);
    float fm = (float)mask[m];
    const float* cp = c + (size_t)m*HH + col;
    float cc = cp[0];
    float cbv = 0.f, cav = 0.f;
    if (lp >= 1)    cbv += cp[-(int)HH];
    if (lp >= 2)    cbv += cp[-2*(int)HH];
    if (lp <= LL-2) cav += cp[HH];
    if (lp <= LL-3) cav += cp[2*HH];
    float s0 = sigm(acc[0][mf][j] + wdv[0]);
    float s1 = sigm(acc[1][mf][j] + wdv[1]);
    float s2 = sigm(acc[2][mf][j] + wdv[2]);
    float s3 = sigm(acc[3][mf][j] + wdv[3]);
    float s4 = sigm(acc[4][mf][j] + wdv[4]);
    float s5 = sigm(acc[5][mf][j] + wdv[5]);
    float u  = tanhf(acc[6][mf][j] + wdv[6]);
    float mx = fmaxf(fmaxf(fmaxf(s0,s1),fmaxf(s2,s3)),s4);
    float e0 = expf(s0-mx), e1 = expf(s1-mx), e2 = expf(s2-mx), e3 = expf(s3-mx), e4 = expf(s4-mx);
    float inv = 1.0f/(e0+e1+e2+e3+e4);
    float cn = (e0*cbv + e1*cav + e2*cc + e3*dcv + e4*u)*inv;
    float hn = s5*tanhf(cn);
    hout[(size_t)m*HH + col] = f2b(hn*fm);
    if (wc)   cout[(size_t)m*HH + col] = cn*fm;
    if (wf32) hf32[(size_t)m*HH + col] = hn*fm;
    // g_f score contribution (masked exp), using CURRENT c
    float s8 = sigm(acc8[mf][j] + gx);
    float e8 = fm * expf(s8);
    num += e8 * cc;
    den += e8;
  }
  // reduce over kg groups (lanes li, li+16, li+32, li+48)
  num += __shfl_xor(num, 16); num += __shfl_xor(num, 32);
  den += __shfl_xor(den, 16); den += __shfl_xor(den, 32);
  if (kg == 0){
    pnumP[(size_t)(m0>>6)*HH + col] = num;
    pdenP[(size_t)(m0>>6)*HH + col] = den;
  }
}

extern "C" void kernel_launch(void* const* d_in, const int* in_sizes, int n_in,
                              void* d_out, int out_size, void* d_ws, size_t ws_size,
                              hipStream_t stream) {
  const float* win   = (const float*)d_in[0];
  const int*   mask  = (const int*)d_in[1];
  // d_in[2] = num_layers (always 3)
  const float* ih    = (const float*)d_in[3];
  const float* ic    = (const float*)d_in[4];
  const float* Wx    = (const float*)d_in[5];
  const float* Wh    = (const float*)d_in[6];
  const float* Wi    = (const float*)d_in[7];
  const float* Wd    = (const float*)d_in[8];
  const float* bias  = (const float*)d_in[9];
  const float* gWx   = (const float*)d_in[10];
  const float* gWh   = (const float*)d_in[11];
  const float* gb    = (const float*)d_in[12];

  const size_t SZ = (size_t)BB*LL*HH;   // 8388608
  char* p = (char*)d_ws;
  auto alloc = [&](size_t bytes)->char*{ char* r = p; p += (bytes + 255) & ~(size_t)255; return r; };
  u16*   hA    = (u16*)  alloc(SZ*2);            // 16MB
  u16*   hB    = (u16*)  alloc(SZ*2);            // 16MB
  float* cA    = (float*)alloc(SZ*4);            // 32MB
  float* cB    = (float*)d_out;                  // d_out doubles as 2nd c buffer
  u16*   Bp    = (u16*)  alloc((size_t)1835008*2);
  u16*   Gp    = (u16*)  alloc((size_t)65536*2);
  float* comb  = (float*)alloc(BB*HH*4);
  float* combc = (float*)alloc(BB*HH*4);
  float* dh0   = (float*)alloc(BB*HH*4);
  float* dh1   = (float*)alloc(BB*HH*4);
  float* dc0   = (float*)alloc(BB*HH*4);
  float* dc1   = (float*)alloc(BB*HH*4);
  float* g_d   = (float*)alloc(BB*HH*4);
  float* g_o   = (float*)alloc(BB*HH*4);
  float* gx2f  = (float*)alloc(BB*HH*4);
  float* wd    = (float*)alloc((size_t)NG*BB*HH*4);
  float* pnumP = (float*)alloc((size_t)512*HH*4);
  float* pdenP = (float*)alloc((size_t)512*HH*4);
  float* pmh   = (float*)alloc((size_t)BB*16*HH*4);
  float* pmc   = (float*)alloc((size_t)BB*16*HH*4);
  float* dhb[2] = {dh0, dh1};
  float* dcb[2] = {dc0, dc1};

  k_wpack<<<7168, 256, 0, stream>>>(Wx, Wh, Wi, Bp);
  k_gw2pack<<<256, 256, 0, stream>>>(gWh, Gp);
  k_init<<<2048, 256, 0, stream>>>(ih, ic, mask, hA, cA);

  u16 *h_cur = hA, *h_nxt = hB;
  float *c_cur = cA, *c_nxt = cB;
  for (int layer = 0; layer < 3; ++layer){
    k_mean1<<<dim3(BB,16), 256, 0, stream>>>(h_cur, c_cur, pmh, pmc);
    k_mean2<<<BB, 256, 0, stream>>>(pmh, pmc, comb, combc);
    const float* dh_l = (layer == 0) ? comb  : dhb[(layer+1)&1];
    const float* dc_l = (layer == 0) ? combc : dcb[(layer+1)&1];
    k_small<<<dim3(BB,8), 256, 0, stream>>>(dh_l, comb, gWx, gWh, gb, Wd, bias, g_d, g_o, gx2f, wd);
    int last = (layer == 2);
    k_main<<<2048, 256, 0, stream>>>(h_cur, c_cur, win, mask, Bp, Gp, wd, dc_l, gx2f,
                                     h_nxt, c_nxt, (float*)d_out, pnumP, pdenP, last, !last);
    k_dummy2<<<BB, 256, 0, stream>>>(pnumP, pdenP, g_d, g_o, dc_l, dhb[layer&1], dcb[layer&1]);
    u16* th = h_cur; h_cur = h_nxt; h_nxt = th;
    float* tc = c_cur; c_cur = c_nxt; c_nxt = tc;
  }
}